// Round 5
// baseline (261.274 us; speedup 1.0000x reference)
//
#include <hip/hip_runtime.h>
#include <stdint.h>

#define K_DIM 4096
#define N_DIM 11008
#define NCOL  1376   // N/8

typedef __attribute__((ext_vector_type(4))) float  f32x4;
typedef __attribute__((ext_vector_type(8))) __bf16 bf16x8;

__device__ __forceinline__ void gload_lds16(const void* g, void* l) {
  __builtin_amdgcn_global_load_lds((const __attribute__((address_space(1))) void*)g,
                                   (__attribute__((address_space(3))) void*)l,
                                   16, 0, 0);
}

// ---------- prologue 1: x fp32 -> bf16 ----------
__global__ void __launch_bounds__(256) convert_x_kernel(const float* __restrict__ x,
                                                        __bf16* __restrict__ a) {
  size_t i = ((size_t)blockIdx.x * 256u + threadIdx.x) * 8u;
  f32x4 v0 = *(const f32x4*)(x + i);
  f32x4 v1 = *(const f32x4*)(x + i + 4);
  bf16x8 o;
  o[0] = (__bf16)v0[0]; o[1] = (__bf16)v0[1]; o[2] = (__bf16)v0[2]; o[3] = (__bf16)v0[3];
  o[4] = (__bf16)v1[0]; o[5] = (__bf16)v1[1]; o[6] = (__bf16)v1[2]; o[7] = (__bf16)v1[3];
  *(bf16x8*)(a + i) = o;
}

// ---------- prologue 2: AWQ dequant -> Wt bf16 [N][K] (transposed via LDS) ----------
__global__ void __launch_bounds__(256) dequant_kernel(const int* __restrict__ qw,
                                                      const int* __restrict__ qz,
                                                      const float* __restrict__ sc,
                                                      __bf16* __restrict__ wt) {
  constexpr int SH[8] = {0, 16, 4, 20, 8, 24, 12, 28};  // AWQ [0,4,1,5,2,6,3,7]*4
  __shared__ __bf16 tile[64][72];
  const int bid = blockIdx.x;
  const int tk = bid & 63;
  const int tn = bid >> 6;
  const int k0 = tk * 64;
  const int c0 = tn * 8;
  const int t = threadIdx.x;
#pragma unroll
  for (int r = 0; r < 2; ++r) {
    int idx = r * 256 + t;
    int kk = idx >> 3;
    int cc = idx & 7;
    int k = k0 + kk;
    int c = c0 + cc;
    uint32_t q  = (uint32_t)qw[(size_t)k * NCOL + c];
    int g = k >> 7;
    uint32_t zq = (uint32_t)qz[(size_t)g * NCOL + c];
    const float* s = sc + (size_t)g * N_DIM + (size_t)c * 8;
#pragma unroll
    for (int j = 0; j < 8; ++j) {
      int wv = (int)((q >> SH[j]) & 15u) - (int)((zq >> SH[j]) & 15u);
      tile[cc * 8 + j][kk] = (__bf16)((float)wv * s[j]);
    }
  }
  __syncthreads();
  const int n0 = tn * 64;
#pragma unroll
  for (int r = 0; r < 2; ++r) {
    int idx = r * 256 + t;
    int row = idx >> 3;
    int kc = idx & 7;
    bf16x8 v = *(const bf16x8*)&tile[row][kc * 8];
    *(bf16x8*)(wt + (size_t)(n0 + row) * K_DIM + k0 + kc * 8) = v;
  }
}

// ---------- main GEMM: 256(M) x 128(N) tile, BK=32, simple 2-barrier loop ----------
// 4 waves (256 thr) as 2M x 2N, per-wave 128x64 = 8x4 frags of 16x16x32 bf16 MFMA.
// BK=32 -> 24KB LDS/block so 3+ blocks/CU co-reside (cross-block stall hiding,
// m114), and grid=688 <= 3*256 slots -> SINGLE dispatch round, util 0.896
// (R2-R4's dominant loss was the 0.67 convoy, not the schedule).
// __launch_bounds__(256,3): forces combined VGPR+AGPR <= ~170 (acc=128 AGPR).
// LDS layout (pair-interleave, conflict-free at 64B rows): row r, logical
// granule g (16B) stored at byte (r>>1)*128 + (r&1)*64 + (g^((r>>1)&3))*16.
// Within each 16-lane b128 phase: 2 lanes/bank = free (m136).
// gload_lds writes linearly (dest = base + cid*16); global source address is
// inverse-permuted to match (rule #21: linear dest + pre-swizzled source).
__global__ void __launch_bounds__(256, 3) wq_gemm_kernel(
    const __bf16* __restrict__ A,    // [M][K] bf16
    const __bf16* __restrict__ Wt,   // [N][K] bf16
    const float* __restrict__ bias,
    float* __restrict__ out,
    const int Mblk)
{
  __shared__ char As[16384];   // 256 rows x 32 bf16, pair-interleaved 128B lines
  __shared__ char Bs[8192];    // 128 rows x 32 bf16, same layout

  const int nwg = gridDim.x;
  int bid = blockIdx.x;
  if ((nwg & 7) == 0) {                 // XCD-aware swizzle (688 % 8 == 0, bijective)
    const int cpx = nwg >> 3;
    bid = (bid & 7) * cpx + (bid >> 3);
  }
  const int bm = bid % Mblk;            // m-fastest: XCD chunk reuses B panels in L2
  const int bn = bid / Mblk;
  const int m0 = bm * 256;
  const int n0 = bn * 128;

  const int t = threadIdx.x;
  const int lane = t & 63;
  const int w = t >> 6;      // 0..3
  const int wr = w >> 1;     // 0..1  (M half: 128 rows)
  const int wc = w & 1;      // 0..1  (N half: 64 cols)
  const int lrow = lane & 15;
  const int lk = lane >> 4;

  // staging source pointers (inverse-permuted for the pair-interleaved layout):
  // dest byte = cid*16; decode r2=cid>>3, j=cid&7, r=2*r2+(j>>2), g=(j&3)^(r2&3)
  const __bf16* srcA[4];
#pragma unroll
  for (int i = 0; i < 4; ++i) {
    const int cid = i * 256 + t;
    const int r2 = cid >> 3;
    const int j = cid & 7;
    const int r = 2 * r2 + (j >> 2);
    const int g = (j & 3) ^ (r2 & 3);
    srcA[i] = A + (size_t)(m0 + r) * K_DIM + g * 8;
  }
  const __bf16* srcB[2];
#pragma unroll
  for (int i = 0; i < 2; ++i) {
    const int cid = i * 256 + t;
    const int r2 = cid >> 3;
    const int r = 2 * r2 + ((cid & 7) >> 2);
    const int g = (cid & 3) ^ (r2 & 3);
    srcB[i] = Wt + (size_t)(n0 + r) * K_DIM + g * 8;
  }

  f32x4 acc[8][4];
#pragma unroll
  for (int i = 0; i < 8; ++i)
#pragma unroll
    for (int j = 0; j < 4; ++j) acc[i][j] = (f32x4){0.f, 0.f, 0.f, 0.f};

  // compute-side bases: q = (lrow>>1)&3 independent of m/n (m*16, wr*128 even)
  const int lane_off = (lrow & 1) * 64 + ((lk ^ ((lrow >> 1) & 3)) << 4);
  const char* abase = As + (wr * 64 + (lrow >> 1)) * 128 + lane_off;
  const char* bbase = Bs + (wc * 32 + (lrow >> 1)) * 128 + lane_off;

  for (int kt = 0; kt < 128; ++kt) {
    __syncthreads();   // previous tile's compute done; LDS reusable
#pragma unroll
    for (int i = 0; i < 4; ++i) {
      gload_lds16(srcA[i], As + i * 4096 + t * 16);
      srcA[i] += 32;
    }
#pragma unroll
    for (int i = 0; i < 2; ++i) {
      gload_lds16(srcB[i], Bs + i * 4096 + t * 16);
      srcB[i] += 32;
    }
    __syncthreads();   // compiler drains vmcnt(0): staged tile visible

    bf16x8 bv[4];
#pragma unroll
    for (int n = 0; n < 4; ++n) bv[n] = *(const bf16x8*)(bbase + n * 1024);
#pragma unroll
    for (int m = 0; m < 8; ++m) {
      const bf16x8 av = *(const bf16x8*)(abase + m * 1024);
#pragma unroll
      for (int n = 0; n < 4; ++n)
        acc[m][n] = __builtin_amdgcn_mfma_f32_16x16x32_bf16(av, bv[n], acc[m][n], 0, 0, 0);
    }
  }

  // epilogue: C/D layout col=lane&15, row=(lane>>4)*4+reg (m89-verified, R1-R4-passed)
  const int orow = m0 + wr * 128 + lk * 4;
  const int ocol = n0 + wc * 64 + lrow;
#pragma unroll
  for (int n = 0; n < 4; ++n) {
    const int col = ocol + n * 16;
    const float bv = bias[col];
#pragma unroll
    for (int m = 0; m < 8; ++m) {
      float* po = out + (size_t)(orow + m * 16) * N_DIM + col;
      po[0]                 = acc[m][n][0] + bv;
      po[(size_t)N_DIM]     = acc[m][n][1] + bv;
      po[2 * (size_t)N_DIM] = acc[m][n][2] + bv;
      po[3 * (size_t)N_DIM] = acc[m][n][3] + bv;
    }
  }
}

extern "C" void kernel_launch(void* const* d_in, const int* in_sizes, int n_in,
                              void* d_out, int out_size, void* d_ws, size_t ws_size,
                              hipStream_t stream) {
  const float* x    = (const float*)d_in[0];
  const int* qw     = (const int*)d_in[1];
  const int* qz     = (const int*)d_in[2];
  const float* sc   = (const float*)d_in[3];
  const float* bias = (const float*)d_in[4];
  float* out = (float*)d_out;

  const int M = in_sizes[0] / K_DIM;        // 2048
  const int Mblk = M / 256;                 // 8
  const int grid = Mblk * (N_DIM / 128);    // 8 * 86 = 688 (divisible by 8)

  const size_t abytes = (size_t)M * K_DIM * 2;
  __bf16* Aw = (__bf16*)d_ws;
  __bf16* Wt = (__bf16*)((char*)d_ws + abytes);

  convert_x_kernel<<<(M * K_DIM) / 2048, 256, 0, stream>>>(x, Aw);
  dequant_kernel<<<(K_DIM / 64) * (N_DIM / 64), 256, 0, stream>>>(qw, qz, sc, Wt);

  wq_gemm_kernel<<<grid, 256, 0, stream>>>(Aw, Wt, bias, out, Mblk);
}